// Round 1
// baseline (5706.429 us; speedup 1.0000x reference)
//
#include <hip/hip_runtime.h>

// Problem constants (from reference setup_inputs): B=32, V=200000, F=400000.
#define EPS 1e-12f

__global__ void zero_kernel(float4* __restrict__ out, int n4) {
    int i = blockIdx.x * blockDim.x + threadIdx.x;
    if (i < n4) out[i] = make_float4(0.f, 0.f, 0.f, 0.f);
}

__global__ void face_scatter_kernel(const float* __restrict__ verts,
                                    const int* __restrict__ faces,
                                    float* __restrict__ out,
                                    int V, int F) {
    int f = blockIdx.x * blockDim.x + threadIdx.x;
    if (f >= F) return;
    int b = blockIdx.y;

    int i0 = faces[3 * f + 0];
    int i1 = faces[3 * f + 1];
    int i2 = faces[3 * f + 2];

    const float* vb = verts + (long long)b * V * 3;

    float v0x = vb[3 * i0 + 0], v0y = vb[3 * i0 + 1], v0z = vb[3 * i0 + 2];
    float v1x = vb[3 * i1 + 0], v1y = vb[3 * i1 + 1], v1z = vb[3 * i1 + 2];
    float v2x = vb[3 * i2 + 0], v2y = vb[3 * i2 + 1], v2z = vb[3 * i2 + 2];

    // e1 = v0 - v1; e2 = v2 - v1; n = cross(e2, e1)
    float e1x = v0x - v1x, e1y = v0y - v1y, e1z = v0z - v1z;
    float e2x = v2x - v1x, e2y = v2y - v1y, e2z = v2z - v1z;

    float nx = e2y * e1z - e2z * e1y;
    float ny = e2z * e1x - e2x * e1z;
    float nz = e2x * e1y - e2y * e1x;

    float* ob = out + (long long)b * V * 3;
    atomicAdd(&ob[3 * i0 + 0], nx);
    atomicAdd(&ob[3 * i0 + 1], ny);
    atomicAdd(&ob[3 * i0 + 2], nz);
    atomicAdd(&ob[3 * i1 + 0], nx);
    atomicAdd(&ob[3 * i1 + 1], ny);
    atomicAdd(&ob[3 * i1 + 2], nz);
    atomicAdd(&ob[3 * i2 + 0], nx);
    atomicAdd(&ob[3 * i2 + 1], ny);
    atomicAdd(&ob[3 * i2 + 2], nz);
}

__global__ void normalize_kernel(float* __restrict__ out, int nverts) {
    int i = blockIdx.x * blockDim.x + threadIdx.x;
    if (i >= nverts) return;
    float x = out[3 * i + 0];
    float y = out[3 * i + 1];
    float z = out[3 * i + 2];
    float sq = x * x + y * y + z * z;
    float s = rsqrtf(fmaxf(sq, EPS));
    out[3 * i + 0] = x * s;
    out[3 * i + 1] = y * s;
    out[3 * i + 2] = z * s;
}

extern "C" void kernel_launch(void* const* d_in, const int* in_sizes, int n_in,
                              void* d_out, int out_size, void* d_ws, size_t ws_size,
                              hipStream_t stream) {
    const float* verts = (const float*)d_in[0];
    const int* faces = (const int*)d_in[1];
    float* out = (float*)d_out;

    const int V = 200000;
    const int F = in_sizes[1] / 3;              // 400000
    const int B = in_sizes[0] / (3 * V);        // 32
    const int nverts = B * V;                   // 6.4M
    const int ntot = in_sizes[0];               // 19.2M floats

    // 1) zero the accumulator (out_size is divisible by 4: 19,200,000 = 4*4.8M)
    int n4 = ntot / 4;
    zero_kernel<<<(n4 + 255) / 256, 256, 0, stream>>>((float4*)out, n4);

    // 2) per-(face,batch) cross product + scatter-add
    dim3 grid((F + 255) / 256, B);
    face_scatter_kernel<<<grid, 256, 0, stream>>>(verts, faces, out, V, F);

    // 3) normalize
    normalize_kernel<<<(nverts + 255) / 256, 256, 0, stream>>>(out, nverts);
}

// Round 2
// 1479.458 us; speedup vs baseline: 3.8571x; 3.8571x over previous
//
#include <hip/hip_runtime.h>

#define EPS 1e-12f

// ---------------------------------------------------------------------------
// CSR-gather implementation:
//   1. zero cursor (V ints)
//   2. count faces per vertex (atomicAdd into cursor)
//   3. exclusive scan cursor -> offsets (single 1024-thread block)
//   4. zero cursor again
//   5. fill csr: for each face corner, slot = offsets[v] + atomicAdd(cursor[v])
//      store the face's three vertex indices (i0,i1,i2) at csr[slot]
//   6. gather: thread per (vertex, batch); recompute incident face normals
//      from L2-resident per-batch vertex data, accumulate, normalize, store.
// ---------------------------------------------------------------------------

__global__ void zero_ints(int* __restrict__ p, int n) {
    int i = blockIdx.x * blockDim.x + threadIdx.x;
    if (i < n) p[i] = 0;
}

__global__ void count_kernel(const int* __restrict__ faces, int* __restrict__ counts, int F) {
    int f = blockIdx.x * blockDim.x + threadIdx.x;
    if (f >= F) return;
    atomicAdd(&counts[faces[3 * f + 0]], 1);
    atomicAdd(&counts[faces[3 * f + 1]], 1);
    atomicAdd(&counts[faces[3 * f + 2]], 1);
}

__global__ __launch_bounds__(1024) void scan_kernel(const int* __restrict__ counts,
                                                    int* __restrict__ offsets, int V) {
    __shared__ int sums[1024];
    int t = threadIdx.x;
    int chunk = (V + 1023) / 1024;
    int start = t * chunk;
    int end = min(start + chunk, V);
    int s = 0;
    for (int i = start; i < end; i++) s += counts[i];
    sums[t] = s;
    __syncthreads();
    // Hillis-Steele inclusive scan over 1024 partials
    for (int off = 1; off < 1024; off <<= 1) {
        int v = (t >= off) ? sums[t - off] : 0;
        __syncthreads();
        sums[t] += v;
        __syncthreads();
    }
    int prefix = (t == 0) ? 0 : sums[t - 1];
    for (int i = start; i < end; i++) {
        offsets[i] = prefix;
        prefix += counts[i];
    }
    if (t == 1023) offsets[V] = sums[1023];
}

__global__ void fill_kernel(const int* __restrict__ faces,
                            const int* __restrict__ offsets,
                            int* __restrict__ cursor,
                            int* __restrict__ csr, int F) {
    int f = blockIdx.x * blockDim.x + threadIdx.x;
    if (f >= F) return;
    int i0 = faces[3 * f + 0];
    int i1 = faces[3 * f + 1];
    int i2 = faces[3 * f + 2];
    int vs[3] = {i0, i1, i2};
#pragma unroll
    for (int c = 0; c < 3; c++) {
        int v = vs[c];
        int pos = offsets[v] + atomicAdd(&cursor[v], 1);
        csr[3 * pos + 0] = i0;
        csr[3 * pos + 1] = i1;
        csr[3 * pos + 2] = i2;
    }
}

__global__ void gather_kernel(const float* __restrict__ verts,
                              const int* __restrict__ offsets,
                              const int* __restrict__ csr,
                              float* __restrict__ out, int V) {
    int v = blockIdx.x * blockDim.x + threadIdx.x;
    if (v >= V) return;
    int b = blockIdx.y;
    const float* vb = verts + (size_t)b * V * 3;
    int s = offsets[v];
    int e = offsets[v + 1];
    float ax = 0.f, ay = 0.f, az = 0.f;
    for (int j = s; j < e; j++) {
        int i0 = csr[3 * j + 0];
        int i1 = csr[3 * j + 1];
        int i2 = csr[3 * j + 2];
        float v0x = vb[3 * i0 + 0], v0y = vb[3 * i0 + 1], v0z = vb[3 * i0 + 2];
        float v1x = vb[3 * i1 + 0], v1y = vb[3 * i1 + 1], v1z = vb[3 * i1 + 2];
        float v2x = vb[3 * i2 + 0], v2y = vb[3 * i2 + 1], v2z = vb[3 * i2 + 2];
        float e1x = v0x - v1x, e1y = v0y - v1y, e1z = v0z - v1z;
        float e2x = v2x - v1x, e2y = v2y - v1y, e2z = v2z - v1z;
        ax += e2y * e1z - e2z * e1y;
        ay += e2z * e1x - e2x * e1z;
        az += e2x * e1y - e2y * e1x;
    }
    float sq = ax * ax + ay * ay + az * az;
    float sc = rsqrtf(fmaxf(sq, EPS));
    size_t o = ((size_t)b * V + v) * 3;
    out[o + 0] = ax * sc;
    out[o + 1] = ay * sc;
    out[o + 2] = az * sc;
}

// ---------------- fallback (R1 atomic-scatter path) ----------------

__global__ void zero_kernel(float4* __restrict__ out, int n4) {
    int i = blockIdx.x * blockDim.x + threadIdx.x;
    if (i < n4) out[i] = make_float4(0.f, 0.f, 0.f, 0.f);
}

__global__ void face_scatter_kernel(const float* __restrict__ verts,
                                    const int* __restrict__ faces,
                                    float* __restrict__ out,
                                    int V, int F) {
    int f = blockIdx.x * blockDim.x + threadIdx.x;
    if (f >= F) return;
    int b = blockIdx.y;
    int i0 = faces[3 * f + 0];
    int i1 = faces[3 * f + 1];
    int i2 = faces[3 * f + 2];
    const float* vb = verts + (long long)b * V * 3;
    float v0x = vb[3 * i0 + 0], v0y = vb[3 * i0 + 1], v0z = vb[3 * i0 + 2];
    float v1x = vb[3 * i1 + 0], v1y = vb[3 * i1 + 1], v1z = vb[3 * i1 + 2];
    float v2x = vb[3 * i2 + 0], v2y = vb[3 * i2 + 1], v2z = vb[3 * i2 + 2];
    float e1x = v0x - v1x, e1y = v0y - v1y, e1z = v0z - v1z;
    float e2x = v2x - v1x, e2y = v2y - v1y, e2z = v2z - v1z;
    float nx = e2y * e1z - e2z * e1y;
    float ny = e2z * e1x - e2x * e1z;
    float nz = e2x * e1y - e2y * e1x;
    float* ob = out + (long long)b * V * 3;
    atomicAdd(&ob[3 * i0 + 0], nx);
    atomicAdd(&ob[3 * i0 + 1], ny);
    atomicAdd(&ob[3 * i0 + 2], nz);
    atomicAdd(&ob[3 * i1 + 0], nx);
    atomicAdd(&ob[3 * i1 + 1], ny);
    atomicAdd(&ob[3 * i1 + 2], nz);
    atomicAdd(&ob[3 * i2 + 0], nx);
    atomicAdd(&ob[3 * i2 + 1], ny);
    atomicAdd(&ob[3 * i2 + 2], nz);
}

__global__ void normalize_kernel(float* __restrict__ out, int nverts) {
    int i = blockIdx.x * blockDim.x + threadIdx.x;
    if (i >= nverts) return;
    float x = out[3 * i + 0];
    float y = out[3 * i + 1];
    float z = out[3 * i + 2];
    float sq = x * x + y * y + z * z;
    float s = rsqrtf(fmaxf(sq, EPS));
    out[3 * i + 0] = x * s;
    out[3 * i + 1] = y * s;
    out[3 * i + 2] = z * s;
}

extern "C" void kernel_launch(void* const* d_in, const int* in_sizes, int n_in,
                              void* d_out, int out_size, void* d_ws, size_t ws_size,
                              hipStream_t stream) {
    const float* verts = (const float*)d_in[0];
    const int* faces = (const int*)d_in[1];
    float* out = (float*)d_out;

    const int V = 200000;
    const int F = in_sizes[1] / 3;           // 400000
    const int B = in_sizes[0] / (3 * V);     // 32
    const int E = 3 * F;                     // 1.2M csr entries

    // workspace layout
    size_t off_bytes = (size_t)(V + 1) * 4;
    size_t cur_bytes = (size_t)V * 4;
    size_t csr_bytes = (size_t)E * 3 * 4;
    size_t need = off_bytes + cur_bytes + csr_bytes;

    if (ws_size >= need) {
        int* offsets = (int*)d_ws;                      // V+1
        int* cursor = offsets + (V + 1);                // V
        int* csr = cursor + V;                          // 3*E

        zero_ints<<<(V + 255) / 256, 256, 0, stream>>>(cursor, V);
        count_kernel<<<(F + 255) / 256, 256, 0, stream>>>(faces, cursor, F);
        scan_kernel<<<1, 1024, 0, stream>>>(cursor, offsets, V);
        zero_ints<<<(V + 255) / 256, 256, 0, stream>>>(cursor, V);
        fill_kernel<<<(F + 255) / 256, 256, 0, stream>>>(faces, offsets, cursor, csr, F);
        dim3 ggrid((V + 255) / 256, B);
        gather_kernel<<<ggrid, 256, 0, stream>>>(verts, offsets, csr, out, V);
    } else {
        // fallback: atomic scatter path
        const int nverts = B * V;
        const int ntot = in_sizes[0];
        int n4 = ntot / 4;
        zero_kernel<<<(n4 + 255) / 256, 256, 0, stream>>>((float4*)out, n4);
        dim3 grid((F + 255) / 256, B);
        face_scatter_kernel<<<grid, 256, 0, stream>>>(verts, faces, out, V, F);
        normalize_kernel<<<(nverts + 255) / 256, 256, 0, stream>>>(out, nverts);
    }
}

// Round 3
// 855.838 us; speedup vs baseline: 6.6676x; 1.7287x over previous
//
#include <hip/hip_runtime.h>

#define EPS 1e-12f
#define NSCAN 256   // scan blocks/threads

// ---------------------------------------------------------------------------
// Pipeline: zero cursor -> count -> scan(3 kernels) -> fill(int2 CSR, atomicSub)
//           -> gather (XCD-swizzled, batch-local L2)
// CSR entry at corner v of face (i0,i1,i2) stores the other two indices (a,b)
// in cyclic order; contribution = (A - v) x (B - v), which equals the
// reference's cross(v2-v1, v0-v1) for every corner (cyclic identity).
// ---------------------------------------------------------------------------

__global__ void zero_ints(int* __restrict__ p, int n) {
    int i = blockIdx.x * blockDim.x + threadIdx.x;
    if (i < n) p[i] = 0;
}

__global__ void count_kernel(const int* __restrict__ faces, int* __restrict__ counts, int F) {
    int f = blockIdx.x * blockDim.x + threadIdx.x;
    if (f >= F) return;
    atomicAdd(&counts[faces[3 * f + 0]], 1);
    atomicAdd(&counts[faces[3 * f + 1]], 1);
    atomicAdd(&counts[faces[3 * f + 2]], 1);
}

// --- 3-phase exclusive scan of counts[V] -> offsets[V+1] ---

__global__ __launch_bounds__(NSCAN) void scan_partials(const int* __restrict__ counts,
                                                       int* __restrict__ partials,
                                                       int V, int chunk) {
    int b = blockIdx.x, t = threadIdx.x;
    int bstart = b * chunk;
    int bend = min(bstart + chunk, V);
    int s = 0;
    for (int i = bstart + t; i < bend; i += NSCAN) s += counts[i];
    __shared__ int red[NSCAN];
    red[t] = s;
    __syncthreads();
    for (int o = NSCAN / 2; o > 0; o >>= 1) {
        if (t < o) red[t] += red[t + o];
        __syncthreads();
    }
    if (t == 0) partials[b] = red[0];
}

__global__ __launch_bounds__(NSCAN) void scan_top(int* __restrict__ partials) {
    __shared__ int s[NSCAN];
    int t = threadIdx.x;
    int v = partials[t];
    s[t] = v;
    __syncthreads();
    for (int o = 1; o < NSCAN; o <<= 1) {
        int u = (t >= o) ? s[t - o] : 0;
        __syncthreads();
        s[t] += u;
        __syncthreads();
    }
    partials[t] = s[t] - v;  // exclusive
}

__global__ __launch_bounds__(NSCAN) void scan_final(const int* __restrict__ counts,
                                                    const int* __restrict__ partials,
                                                    int* __restrict__ offsets,
                                                    int V, int chunk) {
    int b = blockIdx.x, t = threadIdx.x;
    int bstart = b * chunk;
    int bend = min(bstart + chunk, V);
    int sc = (chunk + NSCAN - 1) / NSCAN;
    int tstart = bstart + t * sc;
    int tend = min(tstart + sc, bend);
    int c[8];
    int n = 0, tsum = 0;
    for (int i = tstart; i < tend; i++) {
        int cv = counts[i];
        c[n++] = cv;
        tsum += cv;
    }
    __shared__ int s[NSCAN];
    s[t] = tsum;
    __syncthreads();
    for (int o = 1; o < NSCAN; o <<= 1) {
        int u = (t >= o) ? s[t - o] : 0;
        __syncthreads();
        s[t] += u;
        __syncthreads();
    }
    int run = partials[b] + s[t] - tsum;  // exclusive base for this thread
    n = 0;
    for (int i = tstart; i < tend; i++) {
        offsets[i] = run;
        run += c[n++];
    }
    if (bend == V && tend == V) offsets[V] = run;  // last block; benign same-value race
}

// fill: cursor still holds counts; atomicSub gives unique slot without re-zero
__global__ void fill_kernel(const int* __restrict__ faces,
                            const int* __restrict__ offsets,
                            int* __restrict__ cursor,
                            int2* __restrict__ csr, int F) {
    int f = blockIdx.x * blockDim.x + threadIdx.x;
    if (f >= F) return;
    int i0 = faces[3 * f + 0];
    int i1 = faces[3 * f + 1];
    int i2 = faces[3 * f + 2];
    int vs[3] = {i0, i1, i2};
    int as[3] = {i1, i2, i0};
    int bs[3] = {i2, i0, i1};
#pragma unroll
    for (int c = 0; c < 3; c++) {
        int v = vs[c];
        int old = atomicSub(&cursor[v], 1);
        int pos = offsets[v] + old - 1;
        csr[pos] = make_int2(as[c], bs[c]);
    }
}

__global__ __launch_bounds__(256) void gather_kernel(const float* __restrict__ verts,
                                                     const int* __restrict__ offsets,
                                                     const int2* __restrict__ csr,
                                                     float* __restrict__ out,
                                                     int V, int B, int xpb) {
    // XCD swizzle: blocks i%8 -> XCD (round-robin dispatch); batch changes
    // slowest so all XCDs work one batch at a time (L2-resident verts).
    int i = blockIdx.x;
    int xcd = i & 7;
    int j = i >> 3;
    int batch = j / xpb;
    int sub = j - batch * xpb;
    int xblk = sub * 8 + xcd;
    int v = xblk * 256 + threadIdx.x;
    if (v >= V || batch >= B) return;

    const float* vb = verts + (size_t)batch * V * 3;
    float vx = vb[3 * v + 0], vy = vb[3 * v + 1], vz = vb[3 * v + 2];

    int s = offsets[v];
    int e = offsets[v + 1];
    float ax = 0.f, ay = 0.f, az = 0.f;
    for (int k = s; k < e; k++) {
        int2 p = csr[k];
        const float* A = vb + 3 * (size_t)p.x;
        const float* Bv = vb + 3 * (size_t)p.y;
        float aX = A[0] - vx, aY = A[1] - vy, aZ = A[2] - vz;
        float bX = Bv[0] - vx, bY = Bv[1] - vy, bZ = Bv[2] - vz;
        ax += aY * bZ - aZ * bY;
        ay += aZ * bX - aX * bZ;
        az += aX * bY - aY * bX;
    }
    float sc = rsqrtf(fmaxf(ax * ax + ay * ay + az * az, EPS));
    size_t o = ((size_t)batch * V + v) * 3;
    out[o + 0] = ax * sc;
    out[o + 1] = ay * sc;
    out[o + 2] = az * sc;
}

extern "C" void kernel_launch(void* const* d_in, const int* in_sizes, int n_in,
                              void* d_out, int out_size, void* d_ws, size_t ws_size,
                              hipStream_t stream) {
    const float* verts = (const float*)d_in[0];
    const int* faces = (const int*)d_in[1];
    float* out = (float*)d_out;

    const int V = 200000;
    const int F = in_sizes[1] / 3;           // 400000
    const int B = in_sizes[0] / (3 * V);     // 32
    const int E = 3 * F;                     // 1.2M csr entries

    // workspace layout: offsets[V+1] | cursor[V] | partials[NSCAN] | csr[E] (int2)
    int* offsets = (int*)d_ws;
    int* cursor = offsets + (V + 1);
    int* partials = cursor + V;
    int2* csr = (int2*)(partials + NSCAN);

    const int chunk = (V + NSCAN - 1) / NSCAN;  // 782

    zero_ints<<<(V + 255) / 256, 256, 0, stream>>>(cursor, V);
    count_kernel<<<(F + 255) / 256, 256, 0, stream>>>(faces, cursor, F);
    scan_partials<<<NSCAN, NSCAN, 0, stream>>>(cursor, partials, V, chunk);
    scan_top<<<1, NSCAN, 0, stream>>>(partials);
    scan_final<<<NSCAN, NSCAN, 0, stream>>>(cursor, partials, offsets, V, chunk);
    fill_kernel<<<(F + 255) / 256, 256, 0, stream>>>(faces, offsets, cursor, csr, F);

    int xblocks = (V + 255) / 256;           // 782
    int xpb = (xblocks + 7) / 8;             // 98
    int nblk = 8 * xpb * B;                  // 25088
    gather_kernel<<<nblk, 256, 0, stream>>>(verts, offsets, csr, out, V, B, xpb);
}